// Round 10
// baseline (236.396 us; speedup 1.0000x reference)
//
#include <hip/hip_runtime.h>
#include <hip/hip_bf16.h>

// GCN 2-layer surrogate. LDS counting-sort CSR build (single-atomic-pass) +
// wave-per-node gather (in-order nodes).
//   part:  bucket = dst>>8 (391 x 256 nodes). Per 8192-edge block: per-wave-
//          PAIR LDS hists (4 copies, cuts same-address atomic contention 4x);
//          atomicAdd returns local rank; scan + per-copy bases; one global
//          atomic per bucket claims a run; LDS staging; coalesced write of
//          packed src|(dst&255)<<20.
//   csr:   per bucket (1024 thr): edges in REGISTERS, per-wave hist atomic
//          returns rank (one atomic pass) -> cnt/rowptr (padded x8, ZROW
//          fill), per-wave bases, scatter slot = base+rank (no 2nd atomic).
//   gemm1: MFMA bf16: hs_bf16 = bf16( rsqrt(cnt+1) * (x @ W1) )  (12.8 MB)
//          block 0 zero-fills row ZROW (pad-gather target).
//   agg1:  8 consecutive nodes/wave (8 lanes = 8 dim-octets each); per iter
//          2 int4 index quads + 8 uint4 row gathers in flight, maskless
//          (ZROW pads), fused relu + (64->2) epilogue. Launched as TWO
//          half-grids (diagnostic: exposes build kernels in top-5 profiles).
//   agg2:  4 nodes/wave (16 lanes each), lane-parallel edges on d=2 table.
//
// LESSONS: (R4/R5) LDS f32 atomic-add ~4 cy/lane-op serialized; scatter-
// accumulate dead. (R6) global-atomic CSR scatter = 15x HBM write
// amplification; LDS-staged coalesced writes mandatory. (R7) agg1 is
// request/fetch-bound (duration tracks total gathers); degree-balancing
// useless. (R9) agg1 pinned at ~3.3 TB/s fetch path across 3 structures ->
// pattern roofline; table can't shrink (fp8 fails precision); frontier is
// the build.

#define N_NODES 100000
#define IN_DIM 128
#define HID_DIM 64
#define OUT_DIM 2
#define NBKT 391        // ceil(100000/256) buckets of 256 nodes
#define BCAP 12288      // csr slots per bucket (mean ~9100 padded, >20 sigma)
#define CROUNDS 12      // BCAP / 1024
#define CHUNK 8192
#define ZROW N_NODES    // index of the all-zero row appended to hsb

typedef short bf16x8 __attribute__((ext_vector_type(8)));
typedef float f32x4 __attribute__((ext_vector_type(4)));

__device__ __forceinline__ unsigned short f2bf(float x) {
    unsigned int u = __float_as_uint(x);
    unsigned int r = (u + 0x7FFFu + ((u >> 16) & 1u)) >> 16;   // RNE
    return (unsigned short)r;
}
__device__ __forceinline__ float bflo(unsigned int u) { return __uint_as_float(u << 16); }
__device__ __forceinline__ float bfhi(unsigned int u) { return __uint_as_float(u & 0xFFFF0000u); }
__device__ __forceinline__ int wave_incl_scan(int v, int laneid) {
#pragma unroll
    for (int off = 1; off < 64; off <<= 1) {
        int u = __shfl_up(v, off);
        if (laneid >= off) v += u;
    }
    return v;
}

// ---------------- part: partition edges into fixed-capacity bucket regions ----------------
__global__ __launch_bounds__(512) void part_kernel(const int* __restrict__ ei,
                                                   int* __restrict__ gCursor,
                                                   int* __restrict__ part, int E) {
    __shared__ int hist[4][512];                              // 8 KB (per wave-pair)
    __shared__ int lrow[512], gbase[512];                     // 4 KB
    __shared__ int lpk[CHUNK];                                // 32 KB
    __shared__ short lbkt[CHUNK];                             // 16 KB
    __shared__ int wsum[8], wofs[8];
    const int t = threadIdx.x;
    const int lane = t & 63, wv = t >> 6;
    const int cp = wv >> 1;                                   // hist copy 0..3
    const int base = blockIdx.x * CHUNK;
    const int cntC = min(CHUNK, E - base);

    hist[0][t] = 0; hist[1][t] = 0; hist[2][t] = 0; hist[3][t] = 0;
    __syncthreads();

    int s[16], d[16], rk[16];
    bool val[16];
    if (base + CHUNK <= E) {
#pragma unroll
        for (int i = 0; i < 4; ++i) {
            int4 sv = ((const int4*)(ei + base))[t + i * 512];
            int4 dv = ((const int4*)(ei + E + base))[t + i * 512];
            s[i * 4 + 0] = sv.x; s[i * 4 + 1] = sv.y; s[i * 4 + 2] = sv.z; s[i * 4 + 3] = sv.w;
            d[i * 4 + 0] = dv.x; d[i * 4 + 1] = dv.y; d[i * 4 + 2] = dv.z; d[i * 4 + 3] = dv.w;
            val[i * 4 + 0] = val[i * 4 + 1] = val[i * 4 + 2] = val[i * 4 + 3] = true;
        }
    } else {
#pragma unroll
        for (int i = 0; i < 16; ++i) {
            int e = base + t + i * 512;
            val[i] = (e < E);
            if (val[i]) {
                s[i] = ei[e];
                d[i] = ei[E + e];
            }
        }
    }
    // single atomic pass into the wave-pair's private hist copy
#pragma unroll
    for (int i = 0; i < 16; ++i)
        if (val[i]) rk[i] = atomicAdd(&hist[cp][d[i] >> 8], 1);
    __syncthreads();

    const int h0 = hist[0][t], h1 = hist[1][t], h2 = hist[2][t], h3 = hist[3][t];
    const int v = h0 + h1 + h2 + h3;
    int inc = wave_incl_scan(v, lane);
    if (lane == 63) wsum[wv] = inc;
    __syncthreads();
    if (t < 64) {
        int w = (t < 8) ? wsum[t] : 0;
        int wi = wave_incl_scan(w, t);
        if (t < 8) wofs[t] = wi - w;
    }
    __syncthreads();
    const int excl = inc - v + wofs[wv];
    if (t < NBKT && v > 0) {
        int old = atomicAdd(&gCursor[t], v);
        gbase[t] = t * BCAP + old;
    }
    lrow[t] = excl;
    // convert hist columns to per-copy exclusive bases (column t owned by thread t)
    hist[0][t] = 0;
    hist[1][t] = h0;
    hist[2][t] = h0 + h1;
    hist[3][t] = h0 + h1 + h2;
    __syncthreads();

    // staging by precomputed rank + copy base (no second atomic pass)
#pragma unroll
    for (int i = 0; i < 16; ++i) {
        if (val[i]) {
            int b = d[i] >> 8;
            int pos = lrow[b] + hist[cp][b] + rk[i];
            lpk[pos] = s[i] | ((d[i] & 255) << 20);
            lbkt[pos] = (short)b;
        }
    }
    __syncthreads();

    for (int i = t; i < cntC; i += 512) {
        int b = lbkt[i];
        int g = gbase[b] + (i - lrow[b]);
        if (g < (b + 1) * BCAP)        // overflow guard (never in practice)
            part[g] = lpk[i];
    }
}

// ---------------- csr: per-bucket finalize (cnt/rowptr + src sort) ----------------
__global__ __launch_bounds__(1024) void csr_kernel(const int* __restrict__ part,
                                                   const int* __restrict__ gCursor,
                                                   int* __restrict__ cnt,
                                                   int* __restrict__ rowptr,
                                                   int* __restrict__ csr_src, int n) {
    __shared__ int wcnt[16][256];      // 16 KB: per-wave hist, then per-wave bases
    __shared__ int wsum[4], wofs[4];
    const int b = blockIdx.x, t = threadIdx.x;
    const int lane = t & 63, wv = t >> 6;
    const int start = b * BCAP;
    const int count = min(gCursor[b], BCAP);

    for (int i = t; i < 16 * 256; i += 1024) ((int*)wcnt)[i] = 0;
    __syncthreads();

    int pk[CROUNDS], rk[CROUNDS];
    bool val[CROUNDS];
#pragma unroll
    for (int k = 0; k < CROUNDS; ++k) {
        int i = t + k * 1024;
        val[k] = (i < count);
        pk[k] = val[k] ? part[start + i] : 0;
        if (val[k]) rk[k] = atomicAdd(&wcnt[wv][(pk[k] >> 20) & 255], 1);
    }
    __syncthreads();

    int v = 0, pv = 0;
    if (t < 256) {
        int sum = 0;
#pragma unroll
        for (int w = 0; w < 16; ++w) sum += wcnt[w][t];
        v = sum;
        pv = (v + 7) & ~7;             // padded region size (8-slot multiple)
    }
    int inc = 0;
    if (t < 256) {
        inc = wave_incl_scan(pv, lane);
        if (lane == 63) wsum[wv] = inc;
    }
    __syncthreads();
    if (t < 64) {
        int w = (t < 4) ? wsum[t] : 0;
        int wi = wave_incl_scan(w, t);
        if (t < 4) wofs[t] = wi - w;
    }
    __syncthreads();
    if (t < 256) {
        const int excl = inc - pv + wofs[wv];   // padded exclusive offset (x8)
        const int node = (b << 8) + t;
        if (node < n) {
            cnt[node] = v;
            rowptr[node] = start + excl;
        }
        // fill pad slots with ZROW (maskless agg1 tail)
        for (int j = v; j < pv; ++j) csr_src[start + excl + j] = ZROW;
        int run = excl;                // per-wave scatter bases, in place
#pragma unroll
        for (int w = 0; w < 16; ++w) {
            int c = wcnt[w][t];
            wcnt[w][t] = run;
            run += c;
        }
    }
    __syncthreads();

    // scatter by precomputed rank (no second atomic pass)
#pragma unroll
    for (int k = 0; k < CROUNDS; ++k) {
        if (val[k]) {
            int nodelo = (pk[k] >> 20) & 255;
            csr_src[start + wcnt[wv][nodelo] + rk[k]] = pk[k] & 0xFFFFF;
        }
    }
}

// ---------------- GEMM1 (MFMA bf16): hs_bf16 = bf16(rsqrt(cnt+1) * (x @ W1)) ----------------
__global__ __launch_bounds__(256) void gemm1_kernel(const float* __restrict__ x,
                                                    const float* __restrict__ W1,
                                                    const int* __restrict__ cnt,
                                                    unsigned short* __restrict__ hsb, int n) {
    __shared__ unsigned short sX[64 * 136];   // 17.4 KB
    __shared__ unsigned short sW[64 * 136];   // 17.4 KB (transposed W1)
    const int tid = threadIdx.x;
    const int rbase = blockIdx.x * 64;

    // zero row ZROW (pad-gather target for agg1)
    if (blockIdx.x == 0 && tid < 8)
        ((float4*)&hsb[(unsigned)ZROW * HID_DIM])[tid] = make_float4(0.f, 0.f, 0.f, 0.f);

    // stage W1^T: read [k][c] coalesced as float4, scatter bf16 to [c][k]
    for (int i = tid; i < 2048; i += 256) {
        int k = i >> 4, cq = (i & 15) << 2;
        float4 v = ((const float4*)W1)[i];
        sW[(cq + 0) * 136 + k] = f2bf(v.x);
        sW[(cq + 1) * 136 + k] = f2bf(v.y);
        sW[(cq + 2) * 136 + k] = f2bf(v.z);
        sW[(cq + 3) * 136 + k] = f2bf(v.w);
    }
    // stage x rows as bf16 (row-major, pad 136)
    for (int i = tid; i < 2048; i += 256) {
        int r = i >> 5, kq = (i & 31) << 2;
        int gr = rbase + r;
        float4 v = make_float4(0.f, 0.f, 0.f, 0.f);
        if (gr < n) v = ((const float4*)x)[gr * 32 + (i & 31)];
        ushort4 u;
        u.x = f2bf(v.x); u.y = f2bf(v.y); u.z = f2bf(v.z); u.w = f2bf(v.w);
        *(ushort4*)&sX[r * 136 + kq] = u;
    }
    __syncthreads();

    const int wave = tid >> 6, lane = tid & 63;
    const int quad = lane >> 4, l16 = lane & 15;
    const int rowoff = wave * 16;

    f32x4 acc[4];
#pragma unroll
    for (int t = 0; t < 4; ++t) acc[t] = (f32x4){0.f, 0.f, 0.f, 0.f};

#pragma unroll
    for (int k0 = 0; k0 < 128; k0 += 32) {
        bf16x8 a = *(const bf16x8*)&sX[(rowoff + l16) * 136 + k0 + quad * 8];
#pragma unroll
        for (int t = 0; t < 4; ++t) {
            bf16x8 b = *(const bf16x8*)&sW[(t * 16 + l16) * 136 + k0 + quad * 8];
            acc[t] = __builtin_amdgcn_mfma_f32_16x16x32_bf16(a, b, acc[t], 0, 0, 0);
        }
    }

    // D layout: col = l16, row = quad*4 + reg
#pragma unroll
    for (int r = 0; r < 4; ++r) {
        int grow = rbase + rowoff + quad * 4 + r;
        if (grow < n) {
            float di = rsqrtf((float)cnt[grow] + 1.0f);
#pragma unroll
            for (int t = 0; t < 4; ++t)
                hsb[grow * HID_DIM + t * 16 + l16] = f2bf(acc[t][r] * di);
        }
    }
}

// ---------------- agg1: 8 nodes/wave, 8 gathers in flight, maskless ----------------
// lane l = dim octet 0..7; per iter: 2 index quads (8 edges), 8 uint4 row
// gathers. Pad slots hold ZROW -> gather the zero row, no masking needed.
// Launched twice on half node ranges (profiling visibility; exact grids).
__global__ __launch_bounds__(256) void agg1_kernel(const int* __restrict__ rowptr,
                                                   const int* __restrict__ cnt,
                                                   const int* __restrict__ csr_src,
                                                   const unsigned short* __restrict__ hsb,
                                                   const float* __restrict__ b1,
                                                   const float* __restrict__ W2,
                                                   float* __restrict__ hs2, int nbase) {
    const int node = nbase + blockIdx.x * 32 + (threadIdx.x >> 3);
    const int l = threadIdx.x & 7;
    const unsigned lofs = (unsigned)l * 8;
    const int start = rowptr[node];
    const int deg = cnt[node];
    const int iters = (deg + 7) >> 3;          // padded deg / 8

    f32x4 alo = (f32x4){0.f, 0.f, 0.f, 0.f};   // dims l*8 + {0,2,4,6}
    f32x4 ahi = (f32x4){0.f, 0.f, 0.f, 0.f};   // dims l*8 + {1,3,5,7}

    const int4* qp = (const int4*)(csr_src + start);  // 32B-aligned (8-slot regions)
    int4 ia = make_int4(ZROW, ZROW, ZROW, ZROW), ib = ia;
    if (iters > 0) { ia = qp[0]; ib = qp[1]; }
    for (int it = 0; it < iters; ++it) {
        const bool more = (it + 1 < iters);
        int4 na = more ? qp[2 * it + 2] : make_int4(ZROW, ZROW, ZROW, ZROW);
        int4 nb = more ? qp[2 * it + 3] : make_int4(ZROW, ZROW, ZROW, ZROW);
        uint4 r0 = *(const uint4*)&hsb[(unsigned)ia.x * HID_DIM + lofs];
        uint4 r1 = *(const uint4*)&hsb[(unsigned)ia.y * HID_DIM + lofs];
        uint4 r2 = *(const uint4*)&hsb[(unsigned)ia.z * HID_DIM + lofs];
        uint4 r3 = *(const uint4*)&hsb[(unsigned)ia.w * HID_DIM + lofs];
        uint4 r4 = *(const uint4*)&hsb[(unsigned)ib.x * HID_DIM + lofs];
        uint4 r5 = *(const uint4*)&hsb[(unsigned)ib.y * HID_DIM + lofs];
        uint4 r6 = *(const uint4*)&hsb[(unsigned)ib.z * HID_DIM + lofs];
        uint4 r7 = *(const uint4*)&hsb[(unsigned)ib.w * HID_DIM + lofs];
        alo += (f32x4){bflo(r0.x), bflo(r0.y), bflo(r0.z), bflo(r0.w)};
        ahi += (f32x4){bfhi(r0.x), bfhi(r0.y), bfhi(r0.z), bfhi(r0.w)};
        alo += (f32x4){bflo(r1.x), bflo(r1.y), bflo(r1.z), bflo(r1.w)};
        ahi += (f32x4){bfhi(r1.x), bfhi(r1.y), bfhi(r1.z), bfhi(r1.w)};
        alo += (f32x4){bflo(r2.x), bflo(r2.y), bflo(r2.z), bflo(r2.w)};
        ahi += (f32x4){bfhi(r2.x), bfhi(r2.y), bfhi(r2.z), bfhi(r2.w)};
        alo += (f32x4){bflo(r3.x), bflo(r3.y), bflo(r3.z), bflo(r3.w)};
        ahi += (f32x4){bfhi(r3.x), bfhi(r3.y), bfhi(r3.z), bfhi(r3.w)};
        alo += (f32x4){bflo(r4.x), bflo(r4.y), bflo(r4.z), bflo(r4.w)};
        ahi += (f32x4){bfhi(r4.x), bfhi(r4.y), bfhi(r4.z), bfhi(r4.w)};
        alo += (f32x4){bflo(r5.x), bflo(r5.y), bflo(r5.z), bflo(r5.w)};
        ahi += (f32x4){bfhi(r5.x), bfhi(r5.y), bfhi(r5.z), bfhi(r5.w)};
        alo += (f32x4){bflo(r6.x), bflo(r6.y), bflo(r6.z), bflo(r6.w)};
        ahi += (f32x4){bfhi(r6.x), bfhi(r6.y), bfhi(r6.z), bfhi(r6.w)};
        alo += (f32x4){bflo(r7.x), bflo(r7.y), bflo(r7.z), bflo(r7.w)};
        ahi += (f32x4){bfhi(r7.x), bfhi(r7.y), bfhi(r7.z), bfhi(r7.w)};
        ia = na; ib = nb;
    }

    float a[8];
    a[0] = alo[0]; a[1] = ahi[0]; a[2] = alo[1]; a[3] = ahi[1];
    a[4] = alo[2]; a[5] = ahi[2]; a[6] = alo[3]; a[7] = ahi[3];

    // self-loop term
    {
        uint4 raw = *(const uint4*)&hsb[(unsigned)node * HID_DIM + lofs];
        a[0] += bflo(raw.x); a[1] += bfhi(raw.x);
        a[2] += bflo(raw.y); a[3] += bfhi(raw.y);
        a[4] += bflo(raw.z); a[5] += bfhi(raw.z);
        a[6] += bflo(raw.w); a[7] += bfhi(raw.w);
    }

    const float di = rsqrtf((float)deg + 1.0f);
    float4 bb0 = *(const float4*)&b1[l * 8];
    float4 bb1 = *(const float4*)&b1[l * 8 + 4];
    float t0 = fmaxf(fmaf(di, a[0], bb0.x), 0.0f);
    float t1 = fmaxf(fmaf(di, a[1], bb0.y), 0.0f);
    float t2 = fmaxf(fmaf(di, a[2], bb0.z), 0.0f);
    float t3 = fmaxf(fmaf(di, a[3], bb0.w), 0.0f);
    float t4 = fmaxf(fmaf(di, a[4], bb1.x), 0.0f);
    float t5 = fmaxf(fmaf(di, a[5], bb1.y), 0.0f);
    float t6 = fmaxf(fmaf(di, a[6], bb1.z), 0.0f);
    float t7 = fmaxf(fmaf(di, a[7], bb1.w), 0.0f);

    // W2 rows for dims l*8..l*8+7: [d][2] row-major -> 4 float4
    float4 w0 = *(const float4*)&W2[l * 16];
    float4 w1 = *(const float4*)&W2[l * 16 + 4];
    float4 w2 = *(const float4*)&W2[l * 16 + 8];
    float4 w3 = *(const float4*)&W2[l * 16 + 12];
    float p0 = t0 * w0.x + t1 * w0.z + t2 * w1.x + t3 * w1.z
             + t4 * w2.x + t5 * w2.z + t6 * w3.x + t7 * w3.z;
    float p1 = t0 * w0.y + t1 * w0.w + t2 * w1.y + t3 * w1.w
             + t4 * w2.y + t5 * w2.w + t6 * w3.y + t7 * w3.w;
    // reduce over the 8 dim-octets (xor 1,2,4 stays within the octet group)
    p0 += __shfl_xor(p0, 1);  p1 += __shfl_xor(p1, 1);
    p0 += __shfl_xor(p0, 2);  p1 += __shfl_xor(p1, 2);
    p0 += __shfl_xor(p0, 4);  p1 += __shfl_xor(p1, 4);

    if (l == 0) {
        *(float2*)&hs2[node * OUT_DIM] = make_float2(di * p0, di * p1);
    }
}

// ---------------- agg2: 4 nodes/wave CSR gather d=2 + fused epilogue ----------------
__global__ __launch_bounds__(256) void agg2_kernel(const int* __restrict__ rowptr,
                                                   const int* __restrict__ cnt,
                                                   const int* __restrict__ csr_src,
                                                   const float* __restrict__ hs2,
                                                   const float* __restrict__ b2,
                                                   float* __restrict__ out, int n) {
    int node = blockIdx.x * 16 + (threadIdx.x >> 4);   // grid exact: 6250*16
    int lane = threadIdx.x & 15;
    int start = rowptr[node];
    int deg = cnt[node];

    float a0 = 0.0f, a1 = 0.0f;
    for (int j = lane; j < deg; j += 16) {
        int s = csr_src[start + j];
        float2 v = *(const float2*)&hs2[s * OUT_DIM];
        a0 += v.x;
        a1 += v.y;
    }
#pragma unroll
    for (int off = 8; off > 0; off >>= 1) {      // xor <=8 stays within 16-group
        a0 += __shfl_xor(a0, off);
        a1 += __shfl_xor(a1, off);
    }
    if (lane == 0) {
        float di = rsqrtf((float)deg + 1.0f);
        float2 self = *(const float2*)&hs2[node * OUT_DIM];
        out[node * OUT_DIM + 0] = di * (a0 + self.x) + b2[0];
        out[node * OUT_DIM + 1] = di * (a1 + self.y) + b2[1];
    }
}

extern "C" void kernel_launch(void* const* d_in, const int* in_sizes, int n_in,
                              void* d_out, int out_size, void* d_ws, size_t ws_size,
                              hipStream_t stream) {
    const float* x  = (const float*)d_in[0];
    const int*   ei = (const int*)d_in[1];     // [2][E], row 0 = src, row 1 = dst
    const float* W1 = (const float*)d_in[2];
    const float* b1 = (const float*)d_in[3];
    const float* W2 = (const float*)d_in[4];
    const float* b2 = (const float*)d_in[5];
    float* out = (float*)d_out;

    const int n = N_NODES;
    const int E = in_sizes[1] / 2;

    char* ws = (char*)d_ws;
    int*   gCursor = (int*)  (ws + 0);            // 1.6 KB
    int*   cnt     = (int*)  (ws + (1u << 20));   // 400 KB
    int*   rowptr  = (int*)  (ws + (2u << 20));   // 400 KB
    float* hs2     = (float*)(ws + (3u << 20));   // 800 KB
    // part (19.2 MB) and hsb (12.8 MB + zero row) alias: part is fully
    // consumed by csr_kernel before gemm1_kernel writes hsb.
    int*   part    = (int*)  (ws + (4u << 20));   // NBKT*BCAP*4 = 19.2 MB
    unsigned short* hsb = (unsigned short*)(ws + (4u << 20));
    int*   csr_src = (int*)  (ws + (24u << 20));  // NBKT*BCAP*4 = 19.2 MB

    hipMemsetAsync(gCursor, 0, NBKT * sizeof(int), stream);

    part_kernel<<<(E + CHUNK - 1) / CHUNK, 512, 0, stream>>>(ei, gCursor, part, E);
    csr_kernel<<<NBKT, 1024, 0, stream>>>(part, gCursor, cnt, rowptr, csr_src, n);

    gemm1_kernel<<<(n + 63) / 64, 256, 0, stream>>>(x, W1, cnt, hsb, n);
    // two exact half-grids: 1563*32 = 50016, 1562*32 = 49984 (sum = 100000)
    agg1_kernel<<<1563, 256, 0, stream>>>(rowptr, cnt, csr_src, hsb, b1, W2, hs2, 0);
    agg1_kernel<<<1562, 256, 0, stream>>>(rowptr, cnt, csr_src, hsb, b1, W2, hs2, 50016);
    agg2_kernel<<<n / 16, 256, 0, stream>>>(rowptr, cnt, csr_src, hs2, b2, out, n);
}

// Round 11
// 222.491 us; speedup vs baseline: 1.0625x; 1.0625x over previous
//
#include <hip/hip_runtime.h>
#include <hip/hip_bf16.h>

// GCN 2-layer surrogate. LDS counting-sort CSR build (single-atomic-pass) +
// wave-per-node gather (in-order nodes).
//   part:  bucket = dst>>8 (391 x 256 nodes). Per 8192-edge block: LDS hist
//          atomicAdd RETURNS the edge's local rank (one atomic pass), scan,
//          one global atomic per bucket claims a run, LDS staging by
//          lrow[b]+rank, coalesced write of packed src|(dst&255)<<20.
//   csr:   per bucket (1024 thr): edges in REGISTERS, per-wave hist atomic
//          returns rank (one atomic pass) -> cnt/rowptr (padded x8, ZROW
//          fill), per-wave bases, scatter slot = base+rank (no 2nd atomic).
//   gemm1: MFMA bf16: hs_bf16 = bf16( rsqrt(cnt+1) * (x @ W1) )  (12.8 MB)
//          A-fragments loaded DIRECT from global x (per-k0 the wave covers
//          16 rows x 128B contiguous = line-covering); only W1^T staged in
//          LDS (17.4 KB) -> 8 blocks/CU occupancy. block 0 zero-fills ZROW.
//   agg1:  8 consecutive nodes/wave (8 lanes = 8 dim-octets each); per iter
//          2 int4 index quads + 8 uint4 row gathers in flight, maskless
//          (ZROW pads), fused relu + (64->2) epilogue.  (proven 50.8 us)
//   agg2:  4 nodes/wave (16 lanes each), lane-parallel edges on d=2 table.
//
// LESSONS: (R4/R5) LDS f32 atomic-add ~4 cy/lane-op serialized; scatter-
// accumulate dead. (R6) global-atomic CSR scatter = 15x HBM write
// amplification; LDS-staged coalesced writes mandatory. (R7) agg1 is
// request/fetch-bound; degree-balancing useless. (R9) agg1 pinned at
// ~3.3 TB/s fetch path across 3 structures -> pattern roofline. (R10)
// splitting agg1 costs ~7 us launch overhead; harness re-poison fill =
// 41 us/iter untouchable; all build kernels < 41 us.

#define N_NODES 100000
#define IN_DIM 128
#define HID_DIM 64
#define OUT_DIM 2
#define NBKT 391        // ceil(100000/256) buckets of 256 nodes
#define BCAP 12288      // csr slots per bucket (mean ~9100 padded, >20 sigma)
#define CROUNDS 12      // BCAP / 1024
#define CHUNK 8192
#define ZROW N_NODES    // index of the all-zero row appended to hsb

typedef short bf16x8 __attribute__((ext_vector_type(8)));
typedef float f32x4 __attribute__((ext_vector_type(4)));

__device__ __forceinline__ unsigned short f2bf(float x) {
    unsigned int u = __float_as_uint(x);
    unsigned int r = (u + 0x7FFFu + ((u >> 16) & 1u)) >> 16;   // RNE
    return (unsigned short)r;
}
__device__ __forceinline__ float bflo(unsigned int u) { return __uint_as_float(u << 16); }
__device__ __forceinline__ float bfhi(unsigned int u) { return __uint_as_float(u & 0xFFFF0000u); }
__device__ __forceinline__ int wave_incl_scan(int v, int laneid) {
#pragma unroll
    for (int off = 1; off < 64; off <<= 1) {
        int u = __shfl_up(v, off);
        if (laneid >= off) v += u;
    }
    return v;
}

// ---------------- part: partition edges into fixed-capacity bucket regions ----------------
__global__ __launch_bounds__(512) void part_kernel(const int* __restrict__ ei,
                                                   int* __restrict__ gCursor,
                                                   int* __restrict__ part, int E) {
    __shared__ int hist[512], lrow[512], gbase[512];
    __shared__ int lpk[CHUNK];                                // 32 KB
    __shared__ short lbkt[CHUNK];                             // 16 KB
    __shared__ int wsum[8], wofs[8];
    const int t = threadIdx.x;
    const int lane = t & 63, wv = t >> 6;
    const int base = blockIdx.x * CHUNK;
    const int cntC = min(CHUNK, E - base);

    hist[t] = 0;
    __syncthreads();

    int s[16], d[16], rk[16];
    bool val[16];
    if (base + CHUNK <= E) {
#pragma unroll
        for (int i = 0; i < 4; ++i) {
            int4 sv = ((const int4*)(ei + base))[t + i * 512];
            int4 dv = ((const int4*)(ei + E + base))[t + i * 512];
            s[i * 4 + 0] = sv.x; s[i * 4 + 1] = sv.y; s[i * 4 + 2] = sv.z; s[i * 4 + 3] = sv.w;
            d[i * 4 + 0] = dv.x; d[i * 4 + 1] = dv.y; d[i * 4 + 2] = dv.z; d[i * 4 + 3] = dv.w;
            val[i * 4 + 0] = val[i * 4 + 1] = val[i * 4 + 2] = val[i * 4 + 3] = true;
        }
    } else {
#pragma unroll
        for (int i = 0; i < 16; ++i) {
            int e = base + t + i * 512;
            val[i] = (e < E);
            if (val[i]) {
                s[i] = ei[e];
                d[i] = ei[E + e];
            }
        }
    }
    // single atomic pass: the returned old value IS the edge's local rank
#pragma unroll
    for (int i = 0; i < 16; ++i)
        if (val[i]) rk[i] = atomicAdd(&hist[d[i] >> 8], 1);
    __syncthreads();

    int v = hist[t];
    int inc = wave_incl_scan(v, lane);
    if (lane == 63) wsum[wv] = inc;
    __syncthreads();
    if (t < 64) {
        int w = (t < 8) ? wsum[t] : 0;
        int wi = wave_incl_scan(w, t);
        if (t < 8) wofs[t] = wi - w;
    }
    __syncthreads();
    const int excl = inc - v + wofs[wv];
    if (t < NBKT && v > 0) {
        int old = atomicAdd(&gCursor[t], v);
        gbase[t] = t * BCAP + old;
    }
    lrow[t] = excl;
    __syncthreads();

    // staging by precomputed rank (no second atomic pass)
#pragma unroll
    for (int i = 0; i < 16; ++i) {
        if (val[i]) {
            int b = d[i] >> 8;
            int pos = lrow[b] + rk[i];
            lpk[pos] = s[i] | ((d[i] & 255) << 20);
            lbkt[pos] = (short)b;
        }
    }
    __syncthreads();

    for (int i = t; i < cntC; i += 512) {
        int b = lbkt[i];
        int g = gbase[b] + (i - lrow[b]);
        if (g < (b + 1) * BCAP)        // overflow guard (never in practice)
            part[g] = lpk[i];
    }
}

// ---------------- csr: per-bucket finalize (cnt/rowptr + src sort) ----------------
__global__ __launch_bounds__(1024) void csr_kernel(const int* __restrict__ part,
                                                   const int* __restrict__ gCursor,
                                                   int* __restrict__ cnt,
                                                   int* __restrict__ rowptr,
                                                   int* __restrict__ csr_src, int n) {
    __shared__ int wcnt[16][256];      // 16 KB: per-wave hist, then per-wave bases
    __shared__ int wsum[4], wofs[4];
    const int b = blockIdx.x, t = threadIdx.x;
    const int lane = t & 63, wv = t >> 6;
    const int start = b * BCAP;
    const int count = min(gCursor[b], BCAP);

    for (int i = t; i < 16 * 256; i += 1024) ((int*)wcnt)[i] = 0;
    __syncthreads();

    int pk[CROUNDS], rk[CROUNDS];
    bool val[CROUNDS];
#pragma unroll
    for (int k = 0; k < CROUNDS; ++k) {
        int i = t + k * 1024;
        val[k] = (i < count);
        pk[k] = val[k] ? part[start + i] : 0;
        if (val[k]) rk[k] = atomicAdd(&wcnt[wv][(pk[k] >> 20) & 255], 1);
    }
    __syncthreads();

    int v = 0, pv = 0;
    if (t < 256) {
        int sum = 0;
#pragma unroll
        for (int w = 0; w < 16; ++w) sum += wcnt[w][t];
        v = sum;
        pv = (v + 7) & ~7;             // padded region size (8-slot multiple)
    }
    int inc = 0;
    if (t < 256) {
        inc = wave_incl_scan(pv, lane);
        if (lane == 63) wsum[wv] = inc;
    }
    __syncthreads();
    if (t < 64) {
        int w = (t < 4) ? wsum[t] : 0;
        int wi = wave_incl_scan(w, t);
        if (t < 4) wofs[t] = wi - w;
    }
    __syncthreads();
    if (t < 256) {
        const int excl = inc - pv + wofs[wv];   // padded exclusive offset (x8)
        const int node = (b << 8) + t;
        if (node < n) {
            cnt[node] = v;
            rowptr[node] = start + excl;
        }
        // fill pad slots with ZROW (maskless agg1 tail)
        for (int j = v; j < pv; ++j) csr_src[start + excl + j] = ZROW;
        int run = excl;                // per-wave scatter bases, in place
#pragma unroll
        for (int w = 0; w < 16; ++w) {
            int c = wcnt[w][t];
            wcnt[w][t] = run;
            run += c;
        }
    }
    __syncthreads();

    // scatter by precomputed rank (no second atomic pass)
#pragma unroll
    for (int k = 0; k < CROUNDS; ++k) {
        if (val[k]) {
            int nodelo = (pk[k] >> 20) & 255;
            csr_src[start + wcnt[wv][nodelo] + rk[k]] = pk[k] & 0xFFFFF;
        }
    }
}

// ---------------- GEMM1 (MFMA bf16): hs_bf16 = bf16(rsqrt(cnt+1) * (x @ W1)) ----------------
// A direct-from-global: lane (quad,l16) loads x[row l16][k0*32+quad*8 ..+8]
// (2 x float4). Per k0 the wave touches 16 rows x 128B contiguous = fully
// line-covering, read exactly once. Only W1^T staged in LDS.
__global__ __launch_bounds__(256) void gemm1_kernel(const float* __restrict__ x,
                                                    const float* __restrict__ W1,
                                                    const int* __restrict__ cnt,
                                                    unsigned short* __restrict__ hsb, int n) {
    __shared__ unsigned short sW[64 * 136];   // 17.4 KB (transposed W1)
    const int tid = threadIdx.x;
    const int rbase = blockIdx.x * 64;

    // zero row ZROW (pad-gather target for agg1)
    if (blockIdx.x == 0 && tid < 8)
        ((float4*)&hsb[(unsigned)ZROW * HID_DIM])[tid] = make_float4(0.f, 0.f, 0.f, 0.f);

    // stage W1^T: read [k][c] coalesced as float4, scatter bf16 to [c][k]
    for (int i = tid; i < 2048; i += 256) {
        int k = i >> 4, cq = (i & 15) << 2;
        float4 v = ((const float4*)W1)[i];
        sW[(cq + 0) * 136 + k] = f2bf(v.x);
        sW[(cq + 1) * 136 + k] = f2bf(v.y);
        sW[(cq + 2) * 136 + k] = f2bf(v.z);
        sW[(cq + 3) * 136 + k] = f2bf(v.w);
    }
    __syncthreads();

    const int wave = tid >> 6, lane = tid & 63;
    const int quad = lane >> 4, l16 = lane & 15;
    const int rowoff = wave * 16;
    const int rowA = rbase + rowoff + l16;          // A-fragment source row
    const bool vA = (rowA < n);
    const float4* xp = (const float4*)(x + (vA ? (size_t)rowA * IN_DIM : 0));

    f32x4 acc[4];
#pragma unroll
    for (int t = 0; t < 4; ++t) acc[t] = (f32x4){0.f, 0.f, 0.f, 0.f};

#pragma unroll
    for (int k0 = 0; k0 < 4; ++k0) {
        float4 v0 = xp[k0 * 8 + quad * 2];
        float4 v1 = xp[k0 * 8 + quad * 2 + 1];
        if (!vA) {
            v0 = make_float4(0.f, 0.f, 0.f, 0.f);
            v1 = make_float4(0.f, 0.f, 0.f, 0.f);
        }
        bf16x8 a = (bf16x8){(short)f2bf(v0.x), (short)f2bf(v0.y),
                            (short)f2bf(v0.z), (short)f2bf(v0.w),
                            (short)f2bf(v1.x), (short)f2bf(v1.y),
                            (short)f2bf(v1.z), (short)f2bf(v1.w)};
#pragma unroll
        for (int t = 0; t < 4; ++t) {
            bf16x8 b = *(const bf16x8*)&sW[(t * 16 + l16) * 136 + k0 * 32 + quad * 8];
            acc[t] = __builtin_amdgcn_mfma_f32_16x16x32_bf16(a, b, acc[t], 0, 0, 0);
        }
    }

    // D layout: col = l16, row = quad*4 + reg
#pragma unroll
    for (int r = 0; r < 4; ++r) {
        int grow = rbase + rowoff + quad * 4 + r;
        if (grow < n) {
            float di = rsqrtf((float)cnt[grow] + 1.0f);
#pragma unroll
            for (int t = 0; t < 4; ++t)
                hsb[grow * HID_DIM + t * 16 + l16] = f2bf(acc[t][r] * di);
        }
    }
}

// ---------------- agg1: 8 nodes/wave, 8 gathers in flight, maskless ----------------
// lane l = dim octet 0..7; per iter: 2 index quads (8 edges), 8 uint4 row
// gathers. Pad slots hold ZROW -> gather the zero row, no masking needed.
__global__ __launch_bounds__(256) void agg1_kernel(const int* __restrict__ rowptr,
                                                   const int* __restrict__ cnt,
                                                   const int* __restrict__ csr_src,
                                                   const unsigned short* __restrict__ hsb,
                                                   const float* __restrict__ b1,
                                                   const float* __restrict__ W2,
                                                   float* __restrict__ hs2, int n) {
    const int node = blockIdx.x * 32 + (threadIdx.x >> 3);   // grid exact: 3125*32
    const int l = threadIdx.x & 7;
    const unsigned lofs = (unsigned)l * 8;
    const int start = rowptr[node];
    const int deg = cnt[node];
    const int iters = (deg + 7) >> 3;          // padded deg / 8

    f32x4 alo = (f32x4){0.f, 0.f, 0.f, 0.f};   // dims l*8 + {0,2,4,6}
    f32x4 ahi = (f32x4){0.f, 0.f, 0.f, 0.f};   // dims l*8 + {1,3,5,7}

    const int4* qp = (const int4*)(csr_src + start);  // 32B-aligned (8-slot regions)
    int4 ia = make_int4(ZROW, ZROW, ZROW, ZROW), ib = ia;
    if (iters > 0) { ia = qp[0]; ib = qp[1]; }
    for (int it = 0; it < iters; ++it) {
        const bool more = (it + 1 < iters);
        int4 na = more ? qp[2 * it + 2] : make_int4(ZROW, ZROW, ZROW, ZROW);
        int4 nb = more ? qp[2 * it + 3] : make_int4(ZROW, ZROW, ZROW, ZROW);
        uint4 r0 = *(const uint4*)&hsb[(unsigned)ia.x * HID_DIM + lofs];
        uint4 r1 = *(const uint4*)&hsb[(unsigned)ia.y * HID_DIM + lofs];
        uint4 r2 = *(const uint4*)&hsb[(unsigned)ia.z * HID_DIM + lofs];
        uint4 r3 = *(const uint4*)&hsb[(unsigned)ia.w * HID_DIM + lofs];
        uint4 r4 = *(const uint4*)&hsb[(unsigned)ib.x * HID_DIM + lofs];
        uint4 r5 = *(const uint4*)&hsb[(unsigned)ib.y * HID_DIM + lofs];
        uint4 r6 = *(const uint4*)&hsb[(unsigned)ib.z * HID_DIM + lofs];
        uint4 r7 = *(const uint4*)&hsb[(unsigned)ib.w * HID_DIM + lofs];
        alo += (f32x4){bflo(r0.x), bflo(r0.y), bflo(r0.z), bflo(r0.w)};
        ahi += (f32x4){bfhi(r0.x), bfhi(r0.y), bfhi(r0.z), bfhi(r0.w)};
        alo += (f32x4){bflo(r1.x), bflo(r1.y), bflo(r1.z), bflo(r1.w)};
        ahi += (f32x4){bfhi(r1.x), bfhi(r1.y), bfhi(r1.z), bfhi(r1.w)};
        alo += (f32x4){bflo(r2.x), bflo(r2.y), bflo(r2.z), bflo(r2.w)};
        ahi += (f32x4){bfhi(r2.x), bfhi(r2.y), bfhi(r2.z), bfhi(r2.w)};
        alo += (f32x4){bflo(r3.x), bflo(r3.y), bflo(r3.z), bflo(r3.w)};
        ahi += (f32x4){bfhi(r3.x), bfhi(r3.y), bfhi(r3.z), bfhi(r3.w)};
        alo += (f32x4){bflo(r4.x), bflo(r4.y), bflo(r4.z), bflo(r4.w)};
        ahi += (f32x4){bfhi(r4.x), bfhi(r4.y), bfhi(r4.z), bfhi(r4.w)};
        alo += (f32x4){bflo(r5.x), bflo(r5.y), bflo(r5.z), bflo(r5.w)};
        ahi += (f32x4){bfhi(r5.x), bfhi(r5.y), bfhi(r5.z), bfhi(r5.w)};
        alo += (f32x4){bflo(r6.x), bflo(r6.y), bflo(r6.z), bflo(r6.w)};
        ahi += (f32x4){bfhi(r6.x), bfhi(r6.y), bfhi(r6.z), bfhi(r6.w)};
        alo += (f32x4){bflo(r7.x), bflo(r7.y), bflo(r7.z), bflo(r7.w)};
        ahi += (f32x4){bfhi(r7.x), bfhi(r7.y), bfhi(r7.z), bfhi(r7.w)};
        ia = na; ib = nb;
    }

    float a[8];
    a[0] = alo[0]; a[1] = ahi[0]; a[2] = alo[1]; a[3] = ahi[1];
    a[4] = alo[2]; a[5] = ahi[2]; a[6] = alo[3]; a[7] = ahi[3];

    // self-loop term
    {
        uint4 raw = *(const uint4*)&hsb[(unsigned)node * HID_DIM + lofs];
        a[0] += bflo(raw.x); a[1] += bfhi(raw.x);
        a[2] += bflo(raw.y); a[3] += bfhi(raw.y);
        a[4] += bflo(raw.z); a[5] += bfhi(raw.z);
        a[6] += bflo(raw.w); a[7] += bfhi(raw.w);
    }

    const float di = rsqrtf((float)deg + 1.0f);
    float4 bb0 = *(const float4*)&b1[l * 8];
    float4 bb1 = *(const float4*)&b1[l * 8 + 4];
    float t0 = fmaxf(fmaf(di, a[0], bb0.x), 0.0f);
    float t1 = fmaxf(fmaf(di, a[1], bb0.y), 0.0f);
    float t2 = fmaxf(fmaf(di, a[2], bb0.z), 0.0f);
    float t3 = fmaxf(fmaf(di, a[3], bb0.w), 0.0f);
    float t4 = fmaxf(fmaf(di, a[4], bb1.x), 0.0f);
    float t5 = fmaxf(fmaf(di, a[5], bb1.y), 0.0f);
    float t6 = fmaxf(fmaf(di, a[6], bb1.z), 0.0f);
    float t7 = fmaxf(fmaf(di, a[7], bb1.w), 0.0f);

    // W2 rows for dims l*8..l*8+7: [d][2] row-major -> 4 float4
    float4 w0 = *(const float4*)&W2[l * 16];
    float4 w1 = *(const float4*)&W2[l * 16 + 4];
    float4 w2 = *(const float4*)&W2[l * 16 + 8];
    float4 w3 = *(const float4*)&W2[l * 16 + 12];
    float p0 = t0 * w0.x + t1 * w0.z + t2 * w1.x + t3 * w1.z
             + t4 * w2.x + t5 * w2.z + t6 * w3.x + t7 * w3.z;
    float p1 = t0 * w0.y + t1 * w0.w + t2 * w1.y + t3 * w1.w
             + t4 * w2.y + t5 * w2.w + t6 * w3.y + t7 * w3.w;
    // reduce over the 8 dim-octets (xor 1,2,4 stays within the octet group)
    p0 += __shfl_xor(p0, 1);  p1 += __shfl_xor(p1, 1);
    p0 += __shfl_xor(p0, 2);  p1 += __shfl_xor(p1, 2);
    p0 += __shfl_xor(p0, 4);  p1 += __shfl_xor(p1, 4);

    if (l == 0) {
        *(float2*)&hs2[node * OUT_DIM] = make_float2(di * p0, di * p1);
    }
}

// ---------------- agg2: 4 nodes/wave CSR gather d=2 + fused epilogue ----------------
__global__ __launch_bounds__(256) void agg2_kernel(const int* __restrict__ rowptr,
                                                   const int* __restrict__ cnt,
                                                   const int* __restrict__ csr_src,
                                                   const float* __restrict__ hs2,
                                                   const float* __restrict__ b2,
                                                   float* __restrict__ out, int n) {
    int node = blockIdx.x * 16 + (threadIdx.x >> 4);   // grid exact: 6250*16
    int lane = threadIdx.x & 15;
    int start = rowptr[node];
    int deg = cnt[node];

    float a0 = 0.0f, a1 = 0.0f;
    for (int j = lane; j < deg; j += 16) {
        int s = csr_src[start + j];
        float2 v = *(const float2*)&hs2[s * OUT_DIM];
        a0 += v.x;
        a1 += v.y;
    }
#pragma unroll
    for (int off = 8; off > 0; off >>= 1) {      // xor <=8 stays within 16-group
        a0 += __shfl_xor(a0, off);
        a1 += __shfl_xor(a1, off);
    }
    if (lane == 0) {
        float di = rsqrtf((float)deg + 1.0f);
        float2 self = *(const float2*)&hs2[node * OUT_DIM];
        out[node * OUT_DIM + 0] = di * (a0 + self.x) + b2[0];
        out[node * OUT_DIM + 1] = di * (a1 + self.y) + b2[1];
    }
}

extern "C" void kernel_launch(void* const* d_in, const int* in_sizes, int n_in,
                              void* d_out, int out_size, void* d_ws, size_t ws_size,
                              hipStream_t stream) {
    const float* x  = (const float*)d_in[0];
    const int*   ei = (const int*)d_in[1];     // [2][E], row 0 = src, row 1 = dst
    const float* W1 = (const float*)d_in[2];
    const float* b1 = (const float*)d_in[3];
    const float* W2 = (const float*)d_in[4];
    const float* b2 = (const float*)d_in[5];
    float* out = (float*)d_out;

    const int n = N_NODES;
    const int E = in_sizes[1] / 2;

    char* ws = (char*)d_ws;
    int*   gCursor = (int*)  (ws + 0);            // 1.6 KB
    int*   cnt     = (int*)  (ws + (1u << 20));   // 400 KB
    int*   rowptr  = (int*)  (ws + (2u << 20));   // 400 KB
    float* hs2     = (float*)(ws + (3u << 20));   // 800 KB
    // part (19.2 MB) and hsb (12.8 MB + zero row) alias: part is fully
    // consumed by csr_kernel before gemm1_kernel writes hsb.
    int*   part    = (int*)  (ws + (4u << 20));   // NBKT*BCAP*4 = 19.2 MB
    unsigned short* hsb = (unsigned short*)(ws + (4u << 20));
    int*   csr_src = (int*)  (ws + (24u << 20));  // NBKT*BCAP*4 = 19.2 MB

    hipMemsetAsync(gCursor, 0, NBKT * sizeof(int), stream);

    part_kernel<<<(E + CHUNK - 1) / CHUNK, 512, 0, stream>>>(ei, gCursor, part, E);
    csr_kernel<<<NBKT, 1024, 0, stream>>>(part, gCursor, cnt, rowptr, csr_src, n);

    gemm1_kernel<<<(n + 63) / 64, 256, 0, stream>>>(x, W1, cnt, hsb, n);
    agg1_kernel<<<n / 32, 256, 0, stream>>>(rowptr, cnt, csr_src, hsb, b1, W2, hs2, n);
    agg2_kernel<<<n / 16, 256, 0, stream>>>(rowptr, cnt, csr_src, hs2, b2, out, n);
}